// Round 10
// baseline (133.617 us; speedup 1.0000x reference)
//
#include <hip/hip_runtime.h>
#include <hip/hip_bf16.h>
#include <math.h>

#define N_NODES 50000
#define N_EDGES 800000
#define CAP 32          // bucket row = 32 ushorts = exactly one 64B line
#define MAX_OVF 8192    // overflow list; P(deg>32)~1e-4 -> ~5 nodes, ~50 edges

// Two-phase binning:
#define NBIN 196                    // ceil(N_NODES/256) coarse bins of 256 nodes
#define KA_BLOCKS 256               // binning blocks
#define EPB (N_EDGES / KA_BLOCKS)   // 3125 edges per block (exact)
#define EPB4 3128                   // EPB padded to uint4 multiple (arena stride)

#define UV_BLOCKS 256               // MFMA UV-GEMM: 1024 waves, 3125 tiles (~3/wave)
#define W2_BLOCKS 16
#define P1_GRID (KA_BLOCKS + UV_BLOCKS + W2_BLOCKS)

typedef _Float16 f16x8 __attribute__((ext_vector_type(8)));
typedef float f32x4 __attribute__((ext_vector_type(4)));

// ---------------------------------------------------------------------------
// Phase 1 (fused, all independent work):
//   blocks [0,256):     edge binning via IN-LDS COUNTING SORT -> COMPACT
//                       per-block arena region, written as contiguous uint4
//                       stores (R7 PMC: the old scattered 4B arena stores
//                       caused write-allocate amplification, WRITE 17.9MB on
//                       a 3.4MB dirty set). Compact arena = no overflow path
//                       at all (sum of per-bin counts == EPB by construction).
//   blocks [256,512):   UV prep as MFMA GEMM (verified R8, unchanged).
//   blocks [512,528):   W2 -> f16 (unchanged).
// cur[] poison-base trick: cur[0] untouched = base; cur[16] = ovf cursor
// (bumped only by bucket_kernel for deg>CAP); cur[32] untouched -> node's
// force-scan flag reads 0 via poison-base arithmetic.
// ---------------------------------------------------------------------------
__global__ __launch_bounds__(256) void phase1_kernel(
    const float* __restrict__ x, const float* __restrict__ W1,
    const float* __restrict__ b1, const float* __restrict__ W2,
    const int* __restrict__ ei,
    _Float16* __restrict__ Uh, _Float16* __restrict__ Vh,
    _Float16* __restrict__ w2f,
    unsigned* __restrict__ arena, unsigned* __restrict__ cntA,
    unsigned* __restrict__ offs)
{
    __shared__ unsigned sh_hist[256];      // per-bin counts (bins padded to 256)
    __shared__ unsigned sh_scan[256];      // prefix-sum ping
    __shared__ unsigned sh_cur[256];       // pass-2 scatter cursors
    __shared__ unsigned sh_sorted[EPB4];   // bin-sorted packs

    const int blk = blockIdx.x;
    const int tid = threadIdx.x;

    if (blk < KA_BLOCKS) {
        // ---- pass 1: histogram of dst bins (dst-only read) ----
        sh_hist[tid] = 0;
        if (tid < EPB4 - EPB) sh_sorted[EPB + tid] = 0;   // deterministic pad
        __syncthreads();
        const int e0 = blk * EPB;
        for (int i = tid; i < EPB; i += 256)
            atomicAdd(&sh_hist[(unsigned)ei[N_EDGES + e0 + i] >> 8], 1u);
        __syncthreads();

        // ---- exclusive prefix over 256 bins (Hillis-Steele) ----
        unsigned v = sh_hist[tid];
        sh_scan[tid] = v;
        __syncthreads();
        for (int off = 1; off < 256; off <<= 1) {
            unsigned t = (tid >= off) ? sh_scan[tid - off] : 0u;
            __syncthreads();
            sh_scan[tid] += t;
            __syncthreads();
        }
        const unsigned excl = sh_scan[tid] - v;   // exclusive offset
        sh_cur[tid] = excl;
        if (tid < NBIN) {                          // coalesced [blk][bin] tables
            cntA[(size_t)blk * NBIN + tid] = v;
            offs[(size_t)blk * NBIN + tid] = excl;
        }
        __syncthreads();

        // ---- pass 2: re-read edges, scatter bin-sorted into LDS ----
        for (int i = tid; i < EPB; i += 256) {
            int s = ei[e0 + i];
            int d = ei[N_EDGES + e0 + i];
            unsigned bin = (unsigned)d >> 8;
            unsigned dst = atomicAdd(&sh_cur[bin], 1u);
            sh_sorted[dst] = (unsigned)s | ((unsigned)(d & 255) << 16) | (bin << 24);
        }
        __syncthreads();

        // ---- pass 3: contiguous uint4 write-out (fully coalesced) ----
        uint4* dst4 = (uint4*)(arena + (size_t)blk * EPB4);
        const uint4* src4 = (const uint4*)sh_sorted;
        for (int i = tid; i < EPB4 / 4; i += 256) dst4[i] = src4[i];
        // (entries 3125..3127 are zero pad; offsets+counts sum to 3125,
        //  so bucket_kernel never reads them)
    } else if (blk < KA_BLOCKS + UV_BLOCKS) {
        // ---- UV prep via MFMA (verified R8, unchanged) ----
        const int lane = tid & 63;
        const int m = lane & 15;
        const int q = lane >> 4;
        const int wv  = ((blk - KA_BLOCKS) * 256 + tid) >> 6;   // 0..1023
        const int nwv = UV_BLOCKS * 4;

        f16x8 wafr[4][2], wbfr[4][2];
#pragma unroll
        for (int t = 0; t < 4; ++t) {
            const float* w1r = W1 + (size_t)(t * 16 + m) * 128;
#pragma unroll
            for (int s = 0; s < 2; ++s) {
                const int c0 = 32 * s + q * 8;
                float4 pa0 = *(const float4*)(w1r + c0);
                float4 pa1 = *(const float4*)(w1r + c0 + 4);
                float4 pb0 = *(const float4*)(w1r + 64 + c0);
                float4 pb1 = *(const float4*)(w1r + 64 + c0 + 4);
                float av[8] = {pa0.x, pa0.y, pa0.z, pa0.w,
                               pa1.x, pa1.y, pa1.z, pa1.w};
                float bv[8] = {pb0.x, pb0.y, pb0.z, pb0.w,
                               pb1.x, pb1.y, pb1.z, pb1.w};
#pragma unroll
                for (int j = 0; j < 8; ++j) {
                    wafr[t][s][j] = (_Float16)(av[j] - bv[j]);
                    wbfr[t][s][j] = (_Float16)bv[j];
                }
            }
        }
        float biasv[4];
#pragma unroll
        for (int t = 0; t < 4; ++t) biasv[t] = b1[t * 16 + m];

        for (int tile = wv; tile < N_NODES / 16; tile += nwv) {   // 3125 exact
            const float* xr = x + (size_t)(tile * 16 + m) * 64 + q * 8;
            f16x8 a[2];
#pragma unroll
            for (int s = 0; s < 2; ++s) {
                float4 x0 = *(const float4*)(xr + 32 * s);
                float4 x1 = *(const float4*)(xr + 32 * s + 4);
                float xv[8] = {x0.x, x0.y, x0.z, x0.w, x1.x, x1.y, x1.z, x1.w};
#pragma unroll
                for (int j = 0; j < 8; ++j) a[s][j] = (_Float16)xv[j];
            }
#pragma unroll
            for (int t = 0; t < 4; ++t) {
                f32x4 au = {0.f, 0.f, 0.f, 0.f};
                f32x4 aw = {0.f, 0.f, 0.f, 0.f};
                au = __builtin_amdgcn_mfma_f32_16x16x32_f16(a[0], wafr[t][0], au, 0, 0, 0);
                au = __builtin_amdgcn_mfma_f32_16x16x32_f16(a[1], wafr[t][1], au, 0, 0, 0);
                aw = __builtin_amdgcn_mfma_f32_16x16x32_f16(a[0], wbfr[t][0], aw, 0, 0, 0);
                aw = __builtin_amdgcn_mfma_f32_16x16x32_f16(a[1], wbfr[t][1], aw, 0, 0, 0);
#pragma unroll
                for (int r = 0; r < 4; ++r) {
                    const size_t row = (size_t)(tile * 16 + 4 * q + r) * 64;
                    Uh[row + t * 16 + m] = (_Float16)(au[r] + biasv[t]);
                    Vh[row + t * 16 + m] = (_Float16)aw[r];
                }
            }
        }
    } else {
        const int i = (blk - KA_BLOCKS - UV_BLOCKS) * 256 + tid;
        if (i < 64 * 64) w2f[i] = (_Float16)W2[i];
    }
}

// ---------------------------------------------------------------------------
// Phase 2: one block per coarse bin, 1024 threads. Thread (part,chunk) drains
// quarter [part*n/4,(part+1)*n/4) of the COMPACT (bin,chunk) run located at
// arena[chunk*EPB4 + offs[chunk][bin]] (slot ORDER within a bucket row is
// irrelevant for max). Writes exact per-node counts. ovf only for deg>CAP.
// ---------------------------------------------------------------------------
__global__ __launch_bounds__(1024) void bucket_kernel(
    const unsigned* __restrict__ arena, const unsigned* __restrict__ cntA,
    const unsigned* __restrict__ offs,
    unsigned* __restrict__ counts, unsigned short* __restrict__ buckets,
    unsigned* __restrict__ cur, int2* __restrict__ ovf)
{
    __shared__ unsigned lcnt[256];
    const int bin = blockIdx.x;
    const int tid = threadIdx.x;
    if (tid < 256) lcnt[tid] = 0;
    __syncthreads();

    const unsigned base = cur[0];
    const int chunk = tid & 255;
    const int part  = tid >> 8;                        // 0..3
    const unsigned n  = cntA[(size_t)chunk * NBIN + bin];
    const unsigned st = offs[(size_t)chunk * NBIN + bin];
    const unsigned j0 = (n * (unsigned)part) >> 2;
    const unsigned j1 = (n * (unsigned)(part + 1)) >> 2;
    const unsigned* ch = arena + (size_t)chunk * EPB4 + st;

    for (unsigned j = j0; j < j1; ++j) {
        unsigned p = ch[j];
        unsigned dlow = (p >> 16) & 255u;
        unsigned s = p & 0xFFFFu;
        unsigned pos = atomicAdd(&lcnt[dlow], 1u);
        int d = bin * 256 + (int)dlow;
        if (pos < CAP) {
            buckets[(size_t)d * CAP + pos] = (unsigned short)s;
        } else {
            unsigned o = atomicAdd(&cur[16], 1u) - base;
            if (o < MAX_OVF) ovf[o] = make_int2(d, (int)s);
        }
    }
    __syncthreads();
    if (tid < 256) {
        const int node = bin * 256 + tid;
        if (node < N_NODES) counts[node] = lcnt[tid];
    }
}

// ---------------------------------------------------------------------------
// Tile compute (all-f16): h = leaky(u+v) computed in PACKED f16, single-f16
// A and B -> 2 MFMAs per output quadrant. Masked max over rows 4q+r < lim
// accumulates into rm[4]; q-reduction hoisted to the caller.
//   A: lane m+16q holds A[m][k]   B: lane n+16q holds W2[n][k]
//   D: lane holds D[4q+r][lane&15]
// ---------------------------------------------------------------------------
__device__ __forceinline__ void tile_mfma_max(
    const f16x8* __restrict__ uh, const f16x8* __restrict__ vv,
    const _Float16* __restrict__ w2f, int m, int q, int lim,
    float* __restrict__ rm)
{
    f16x8 a[2];
#pragma unroll
    for (int s = 0; s < 2; ++s) {
        f16x8 h  = uh[s] + vv[s];
        f16x8 hs = h * (_Float16)0.01f;          // LeakyReLU = max(h, .01h)
#pragma unroll
        for (int j = 0; j < 8; ++j)
            a[s][j] = (h[j] > hs[j]) ? h[j] : hs[j];
    }
#pragma unroll
    for (int t = 0; t < 4; ++t) {
        const f16x8 b0 = *(const f16x8*)(w2f + (t * 16 + m) * 64 + q * 8);
        const f16x8 b1 = *(const f16x8*)(w2f + (t * 16 + m) * 64 + 32 + q * 8);
        f32x4 acc = {0.f, 0.f, 0.f, 0.f};
        acc = __builtin_amdgcn_mfma_f32_16x16x32_f16(a[0], b0, acc, 0, 0, 0);
        acc = __builtin_amdgcn_mfma_f32_16x16x32_f16(a[1], b1, acc, 0, 0, 0);
        float v = -INFINITY;
#pragma unroll
        for (int r = 0; r < 4; ++r)
            if (4 * q + r < lim) v = fmaxf(v, acc[r]);   // mask garbage rows
        rm[t] = fmaxf(rm[t], v);                 // q-reduce deferred to caller
    }
}

// f16 row gather (U and V share the layout): the 4 q-lanes of one row cover
// a full 64B line per instruction.
__device__ __forceinline__ void load_vh(const _Float16* __restrict__ Vh,
                                        unsigned si, int q, f16x8* vv)
{
    const _Float16* b0 = Vh + (size_t)si * 64 + q * 8;
    vv[0] = *(const f16x8*)b0;
    vv[1] = *(const f16x8*)(b0 + 32);
}

// tanh via hw exp + rcp: ~7 VALU vs libm's ~20+.
__device__ __forceinline__ float fast_tanh(float x)
{
    float xc = fminf(fmaxf(x, -12.f), 12.f);
    float e  = __expf(2.f * xc);
    return 1.f - 2.f * __builtin_amdgcn_rcpf(e + 1.f);
}

// ---------------------------------------------------------------------------
// K3: wave per node, 2-deep software pipeline — BYTE-IDENTICAL to R8
// (all-f16 data, 2-MFMA quadrants, addr-only tile-1 prefetch, deferred
// q-reduction, fast tanh). cur[32] is now never bumped -> force==0 via the
// poison-base arithmetic. Grid 1024 @ (256,4).
// ---------------------------------------------------------------------------
__global__ __launch_bounds__(256, 4) void node_kernel(
    const unsigned* __restrict__ counts, const unsigned short* __restrict__ buckets,
    const int2* __restrict__ ovf,
    const _Float16* __restrict__ Uh, const _Float16* __restrict__ Vh,
    const _Float16* __restrict__ w2f, const float* __restrict__ b2,
    float* __restrict__ out, const unsigned* __restrict__ cur)
{
    const int lane = threadIdx.x & 63;
    const int m    = lane & 15;
    const int q    = lane >> 4;
    const int wave = (int)((blockIdx.x * blockDim.x + threadIdx.x) >> 6);
    const int nwav = (int)((gridDim.x * blockDim.x) >> 6);

    const float b2v = b2[lane];
    const unsigned base  = cur[0];
    const unsigned force = cur[32] - base;   // never bumped -> 0
    const unsigned nou   = cur[16] - base;   // total ovf entries

    // ---- prologue: arm node A fully; arm bkt/cnt for node B ----
    const int nA0 = wave;                        // wave < 4096 < N_NODES
    int pB = nA0 + nwav; if (pB >= N_NODES) pB = N_NODES - 1;

    unsigned cntAa = counts[nA0];
    int bktA  = buckets[nA0 * CAP + m];
    int bkt2A = buckets[nA0 * CAP + 16 + m];     // same 64B line: free
    f16x8 uhA[2];
    load_vh(Uh, (unsigned)nA0, q, uhA);
    unsigned cntB = counts[pB];
    int bktB  = buckets[pB * CAP + m];
    int bkt2B = buckets[pB * CAP + 16 + m];

    f16x8 vA[2];
    {
        unsigned usiA = (unsigned)bktA;
        if (usiA >= N_NODES) usiA = N_NODES - 1;   // poison-safe clamp
        load_vh(Vh, usiA, q, vA);
    }
    f16x8 uhB[2];
    load_vh(Uh, (unsigned)pB, q, uhB);

    for (int n = nA0; n < N_NODES; n += nwav) {
        int pC = n + 2 * nwav; if (pC >= N_NODES) pC = N_NODES - 1;

        // (1) issue V for node B (bktB arrived during previous compute)
        unsigned usiB = (unsigned)bktB;
        if (usiB >= N_NODES) usiB = N_NODES - 1;
        f16x8 vB[2];
        load_vh(Vh, usiB, q, vB);

        // (2) issue bkt/cnt for node C
        unsigned cntC = counts[pC];
        int bktC  = buckets[pC * CAP + m];
        int bkt2C = buckets[pC * CAP + 16 + m];

        // (3) compute node A = n
        const unsigned c = cntAa;
        const int deg = (c < CAP) ? (int)c : CAP;

        float rm[4] = {-INFINITY, -INFINITY, -INFINITY, -INFINITY};
        const int lim0 = (deg < 16) ? deg : 16;
        tile_mfma_max(uhA, vA, w2f, m, q, lim0, rm);      // tile 0 (pre-armed)

        if (deg > 16) {                                   // tile 1: addr pre-armed
            unsigned si2 = (unsigned)bkt2A;               // entry 16+m; garbage
            if (si2 >= N_NODES) si2 = N_NODES - 1;        // rows masked by lim
            f16x8 v2[2];
            load_vh(Vh, si2, q, v2);
            tile_mfma_max(uhA, v2, w2f, m, q, deg - 16, rm);
        }

        if (c > CAP || force != 0u) {   // exact-correctness fallback
            int no = (nou < MAX_OVF) ? (int)nou : MAX_OVF;
            for (int o = 0; o < no; ++o) {
                const int2 ds = ovf[o];
                if (ds.x != n) continue;
                f16x8 vo[2];
                load_vh(Vh, (unsigned)ds.y, q, vo);
                tile_mfma_max(uhA, vo, w2f, m, q, 16, rm);
            }
        }

        // deferred q-reduction (once per node)
#pragma unroll
        for (int t = 0; t < 4; ++t) {
            rm[t] = fmaxf(rm[t], __shfl_xor(rm[t], 16, 64));
            rm[t] = fmaxf(rm[t], __shfl_xor(rm[t], 32, 64));
        }
        const float sel = (q == 0) ? rm[0] : (q == 1) ? rm[1]
                        : (q == 2) ? rm[2] : rm[3];      // col == lane
        out[(size_t)n * 64 + lane] = (c != 0u) ? fast_tanh(sel + b2v) : 0.f;

        // (4) rotate pipeline state; issue U for next B
        cntAa = cntB; cntB = cntC;
        bktB = bktC; bkt2A = bkt2B; bkt2B = bkt2C;
#pragma unroll
        for (int i = 0; i < 2; ++i) { uhA[i] = uhB[i]; vA[i] = vB[i]; }
        load_vh(Uh, (unsigned)pC, q, uhB);               // next iter's B == pC
    }
}

// ---------------------------------------------------------------------------
extern "C" void kernel_launch(void* const* d_in, const int* in_sizes, int n_in,
                              void* d_out, int out_size, void* d_ws, size_t ws_size,
                              hipStream_t stream)
{
    const float* x  = (const float*)d_in[0];
    const int*   ei = (const int*)d_in[1];
    const float* W1 = (const float*)d_in[2];
    const float* b1 = (const float*)d_in[3];
    const float* W2 = (const float*)d_in[4];
    const float* b2 = (const float*)d_in[5];
    float* out = (float*)d_out;

    char* p = (char*)d_ws;
    _Float16* Uh = (_Float16*)p;           p += (size_t)N_NODES * 64 * 2;
    _Float16* Vh = (_Float16*)p;           p += (size_t)N_NODES * 64 * 2;
    unsigned* arena = (unsigned*)p;        p += (size_t)KA_BLOCKS * EPB4 * 4;
    unsigned short* buckets = (unsigned short*)p;
                                           p += (size_t)N_NODES * CAP * 2;
    _Float16* w2f = (_Float16*)p;          p += 64 * 64 * 2;
    unsigned* cntA = (unsigned*)p;         p += (size_t)KA_BLOCKS * NBIN * 4;
    unsigned* offs = (unsigned*)p;         p += (size_t)KA_BLOCKS * NBIN * 4;
    unsigned* counts = (unsigned*)p;       p += (size_t)((N_NODES + 63) / 64) * 64 * 4;
    unsigned* cur = (unsigned*)p;          p += 64 * 4;
    int2* ovf = (int2*)p;                  p += (size_t)MAX_OVF * 8;

    phase1_kernel<<<P1_GRID, 256, 0, stream>>>(x, W1, b1, W2, ei,
                                               Uh, Vh, w2f,
                                               arena, cntA, offs);
    bucket_kernel<<<NBIN, 1024, 0, stream>>>(arena, cntA, offs,
                                             counts, buckets, cur, ovf);
    node_kernel<<<1024, 256, 0, stream>>>(counts, buckets, ovf,
                                          Uh, Vh, w2f, b2, out, cur);
}

// Round 11
// 127.695 us; speedup vs baseline: 1.0464x; 1.0464x over previous
//
#include <hip/hip_runtime.h>
#include <hip/hip_bf16.h>
#include <math.h>

#define N_NODES 50000
#define N_EDGES 800000
#define CAP 32          // bucket row = 32 ushorts = exactly one 64B line
#define MAX_OVF 8192    // overflow list; P(deg>32)~1e-4 -> ~5 nodes, ~50 edges

// Two-phase binning (R8 scatter version — measured best; R9/R10's counting
// sort was neutral-to-negative):
#define NBIN 196                    // ceil(N_NODES/256) coarse bins of 256 nodes
#define KA_BLOCKS 256               // binning blocks
#define EPB (N_EDGES / KA_BLOCKS)   // 3125 edges per block (exact)
#define SUBCAP 48                   // per-(bin,block) arena cap: mean 16, sigma 4 -> 8 sigma

#define UV_BLOCKS 256               // MFMA UV-GEMM: 1024 waves, 3125 tiles (~3/wave)
#define W2_BLOCKS 16
#define P1_GRID (KA_BLOCKS + UV_BLOCKS + W2_BLOCKS)

typedef _Float16 f16x8 __attribute__((ext_vector_type(8)));
typedef float f32x4 __attribute__((ext_vector_type(4)));

// ---------------------------------------------------------------------------
// Phase 1 (fused, all independent work) — byte-identical to R8 (130.8 µs):
//   blocks [0,256):     edge binning -> per-(bin,block) arena chunks (LDS
//                       histogram+rank; zero global atomics common path).
//   blocks [256,512):   UV prep as MFMA GEMM (verified R8).
//   blocks [512,528):   W2 -> f16.
// cur[] poison-base trick: cur[0] untouched = base; cur[16] = ovf cursor;
// cur[32] = arena-overflow force-scan flag.
// ---------------------------------------------------------------------------
__global__ __launch_bounds__(256) void phase1_kernel(
    const float* __restrict__ x, const float* __restrict__ W1,
    const float* __restrict__ b1, const float* __restrict__ W2,
    const int* __restrict__ ei,
    _Float16* __restrict__ Uh, _Float16* __restrict__ Vh,
    _Float16* __restrict__ w2f,
    unsigned* __restrict__ arena, unsigned* __restrict__ cntA,
    unsigned* __restrict__ cur, int2* __restrict__ ovf)
{
    __shared__ unsigned sh_hist[256];
    __shared__ unsigned sh_pack[EPB];        // src | dlow<<16 | bin<<24
    __shared__ unsigned short sh_rank[EPB];  // rank within (block,bin)

    const int blk = blockIdx.x;
    const int tid = threadIdx.x;

    if (blk < KA_BLOCKS) {
        // ---- edge binning ----
        sh_hist[tid] = 0;
        __syncthreads();
        const int e0 = blk * EPB;
        for (int i = tid; i < EPB; i += 256) {
            int s = ei[e0 + i];
            int d = ei[N_EDGES + e0 + i];
            unsigned bin = (unsigned)d >> 8;
            unsigned r = atomicAdd(&sh_hist[bin], 1u);
            sh_pack[i] = (unsigned)s | ((unsigned)(d & 255) << 16) | (bin << 24);
            sh_rank[i] = (unsigned short)r;
        }
        __syncthreads();
        if (tid < NBIN) cntA[tid * KA_BLOCKS + blk] = sh_hist[tid];
        const unsigned base = cur[0];
        for (int i = tid; i < EPB; i += 256) {
            unsigned p = sh_pack[i];
            unsigned r = sh_rank[i];
            unsigned bin = p >> 24;
            if (r < SUBCAP) {
                arena[((size_t)bin * KA_BLOCKS + blk) * SUBCAP + r] = p;
            } else {
                // arena overflow (statistically never): exact fallback
                atomicAdd(&cur[32], 1u);  // force node_kernel to scan ovf
                unsigned o = atomicAdd(&cur[16], 1u) - base;
                int d = (int)(bin * 256 + ((p >> 16) & 255u));
                int s = (int)(p & 0xFFFFu);
                if (o < MAX_OVF) ovf[o] = make_int2(d, s);
            }
        }
    } else if (blk < KA_BLOCKS + UV_BLOCKS) {
        // ---- UV prep via MFMA (verified R8, unchanged) ----
        const int lane = tid & 63;
        const int m = lane & 15;
        const int q = lane >> 4;
        const int wv  = ((blk - KA_BLOCKS) * 256 + tid) >> 6;   // 0..1023
        const int nwv = UV_BLOCKS * 4;

        f16x8 wafr[4][2], wbfr[4][2];
#pragma unroll
        for (int t = 0; t < 4; ++t) {
            const float* w1r = W1 + (size_t)(t * 16 + m) * 128;
#pragma unroll
            for (int s = 0; s < 2; ++s) {
                const int c0 = 32 * s + q * 8;
                float4 pa0 = *(const float4*)(w1r + c0);
                float4 pa1 = *(const float4*)(w1r + c0 + 4);
                float4 pb0 = *(const float4*)(w1r + 64 + c0);
                float4 pb1 = *(const float4*)(w1r + 64 + c0 + 4);
                float av[8] = {pa0.x, pa0.y, pa0.z, pa0.w,
                               pa1.x, pa1.y, pa1.z, pa1.w};
                float bv[8] = {pb0.x, pb0.y, pb0.z, pb0.w,
                               pb1.x, pb1.y, pb1.z, pb1.w};
#pragma unroll
                for (int j = 0; j < 8; ++j) {
                    wafr[t][s][j] = (_Float16)(av[j] - bv[j]);
                    wbfr[t][s][j] = (_Float16)bv[j];
                }
            }
        }
        float biasv[4];
#pragma unroll
        for (int t = 0; t < 4; ++t) biasv[t] = b1[t * 16 + m];

        for (int tile = wv; tile < N_NODES / 16; tile += nwv) {   // 3125 exact
            const float* xr = x + (size_t)(tile * 16 + m) * 64 + q * 8;
            f16x8 a[2];
#pragma unroll
            for (int s = 0; s < 2; ++s) {
                float4 x0 = *(const float4*)(xr + 32 * s);
                float4 x1 = *(const float4*)(xr + 32 * s + 4);
                float xv[8] = {x0.x, x0.y, x0.z, x0.w, x1.x, x1.y, x1.z, x1.w};
#pragma unroll
                for (int j = 0; j < 8; ++j) a[s][j] = (_Float16)xv[j];
            }
#pragma unroll
            for (int t = 0; t < 4; ++t) {
                f32x4 au = {0.f, 0.f, 0.f, 0.f};
                f32x4 aw = {0.f, 0.f, 0.f, 0.f};
                au = __builtin_amdgcn_mfma_f32_16x16x32_f16(a[0], wafr[t][0], au, 0, 0, 0);
                au = __builtin_amdgcn_mfma_f32_16x16x32_f16(a[1], wafr[t][1], au, 0, 0, 0);
                aw = __builtin_amdgcn_mfma_f32_16x16x32_f16(a[0], wbfr[t][0], aw, 0, 0, 0);
                aw = __builtin_amdgcn_mfma_f32_16x16x32_f16(a[1], wbfr[t][1], aw, 0, 0, 0);
#pragma unroll
                for (int r = 0; r < 4; ++r) {
                    const size_t row = (size_t)(tile * 16 + 4 * q + r) * 64;
                    Uh[row + t * 16 + m] = (_Float16)(au[r] + biasv[t]);
                    Vh[row + t * 16 + m] = (_Float16)aw[r];
                }
            }
        }
    } else {
        const int i = (blk - KA_BLOCKS - UV_BLOCKS) * 256 + tid;
        if (i < 64 * 64) w2f[i] = (_Float16)W2[i];
    }
}

// ---------------------------------------------------------------------------
// Phase 2: one block per coarse bin, 1024 threads (R8 version). Thread
// (part,chunk) drains quarter [part*n/4,(part+1)*n/4) of arena chunk 'chunk'
// (slot ORDER within a bucket row is irrelevant for max). Exact counts out.
// ---------------------------------------------------------------------------
__global__ __launch_bounds__(1024) void bucket_kernel(
    const unsigned* __restrict__ arena, const unsigned* __restrict__ cntA,
    unsigned* __restrict__ counts, unsigned short* __restrict__ buckets,
    unsigned* __restrict__ cur, int2* __restrict__ ovf)
{
    __shared__ unsigned lcnt[256];
    const int bin = blockIdx.x;
    const int tid = threadIdx.x;
    if (tid < 256) lcnt[tid] = 0;
    __syncthreads();

    const unsigned base = cur[0];
    const int chunk = tid & 255;
    const int part  = tid >> 8;                        // 0..3
    unsigned n = cntA[(size_t)bin * KA_BLOCKS + chunk];
    if (n > SUBCAP) n = SUBCAP;                        // excess went to ovf
    const unsigned j0 = (n * (unsigned)part) >> 2;
    const unsigned j1 = (n * (unsigned)(part + 1)) >> 2;
    const unsigned* ch = arena + ((size_t)bin * KA_BLOCKS + chunk) * SUBCAP;

    for (unsigned j = j0; j < j1; ++j) {
        unsigned p = ch[j];
        unsigned dlow = (p >> 16) & 255u;
        unsigned s = p & 0xFFFFu;
        unsigned pos = atomicAdd(&lcnt[dlow], 1u);
        int d = bin * 256 + (int)dlow;
        if (pos < CAP) {
            buckets[(size_t)d * CAP + pos] = (unsigned short)s;
        } else {
            unsigned o = atomicAdd(&cur[16], 1u) - base;
            if (o < MAX_OVF) ovf[o] = make_int2(d, (int)s);
        }
    }
    __syncthreads();
    if (tid < 256) {
        const int node = bin * 256 + tid;
        if (node < N_NODES) counts[node] = lcnt[tid];
    }
}

// ---------------------------------------------------------------------------
// Tile compute (all-f16): h = leaky(u+v) in PACKED f16. R11 change: the
// LeakyReLU select is now __builtin_elementwise_max -> v_pk_max_f16 (4 ops
// per s-half vs 16 scalar cmp+cndmask; R6 PMC: node is VALU-issue bound at
// the 4-wave/SIMD register cap, so packed-op cuts are the remaining lever).
// Max semantics identical -> bit-identical output.
//   A: lane m+16q holds A[m][k]   B: lane n+16q holds W2[n][k]
//   D: lane holds D[4q+r][lane&15]
// ---------------------------------------------------------------------------
__device__ __forceinline__ void tile_mfma_max(
    const f16x8* __restrict__ uh, const f16x8* __restrict__ vv,
    const _Float16* __restrict__ w2f, int m, int q, int lim,
    float* __restrict__ rm)
{
    f16x8 a[2];
#pragma unroll
    for (int s = 0; s < 2; ++s) {
        f16x8 h  = uh[s] + vv[s];
        f16x8 hs = h * (_Float16)0.01f;          // LeakyReLU = max(h, .01h)
#if __has_builtin(__builtin_elementwise_max)
        a[s] = __builtin_elementwise_max(h, hs); // v_pk_max_f16 x4
#else
#pragma unroll
        for (int j = 0; j < 8; ++j)
            a[s][j] = (h[j] > hs[j]) ? h[j] : hs[j];
#endif
    }
#pragma unroll
    for (int t = 0; t < 4; ++t) {
        const f16x8 b0 = *(const f16x8*)(w2f + (t * 16 + m) * 64 + q * 8);
        const f16x8 b1 = *(const f16x8*)(w2f + (t * 16 + m) * 64 + 32 + q * 8);
        f32x4 acc = {0.f, 0.f, 0.f, 0.f};
        acc = __builtin_amdgcn_mfma_f32_16x16x32_f16(a[0], b0, acc, 0, 0, 0);
        acc = __builtin_amdgcn_mfma_f32_16x16x32_f16(a[1], b1, acc, 0, 0, 0);
        float v = -INFINITY;
#pragma unroll
        for (int r = 0; r < 4; ++r)
            if (4 * q + r < lim) v = fmaxf(v, acc[r]);   // mask garbage rows
        rm[t] = fmaxf(rm[t], v);                 // q-reduce deferred to caller
    }
}

// f16 row gather (U and V share the layout): the 4 q-lanes of one row cover
// a full 64B line per instruction.
__device__ __forceinline__ void load_vh(const _Float16* __restrict__ Vh,
                                        unsigned si, int q, f16x8* vv)
{
    const _Float16* b0 = Vh + (size_t)si * 64 + q * 8;
    vv[0] = *(const f16x8*)b0;
    vv[1] = *(const f16x8*)(b0 + 32);
}

// tanh via hw exp + rcp: ~7 VALU vs libm's ~20+.
__device__ __forceinline__ float fast_tanh(float x)
{
    float xc = fminf(fmaxf(x, -12.f), 12.f);
    float e  = __expf(2.f * xc);
    return 1.f - 2.f * __builtin_amdgcn_rcpf(e + 1.f);
}

// ---------------------------------------------------------------------------
// K3: wave per node, 2-deep software pipeline — R8 structure (all-f16 data,
// 2-MFMA quadrants, addr-only tile-1 prefetch, deferred q-reduction, fast
// tanh) with the pk_max repack. Grid 1024 @ (256,4).
// ---------------------------------------------------------------------------
__global__ __launch_bounds__(256, 4) void node_kernel(
    const unsigned* __restrict__ counts, const unsigned short* __restrict__ buckets,
    const int2* __restrict__ ovf,
    const _Float16* __restrict__ Uh, const _Float16* __restrict__ Vh,
    const _Float16* __restrict__ w2f, const float* __restrict__ b2,
    float* __restrict__ out, const unsigned* __restrict__ cur)
{
    const int lane = threadIdx.x & 63;
    const int m    = lane & 15;
    const int q    = lane >> 4;
    const int wave = (int)((blockIdx.x * blockDim.x + threadIdx.x) >> 6);
    const int nwav = (int)((gridDim.x * blockDim.x) >> 6);

    const float b2v = b2[lane];
    const unsigned base  = cur[0];
    const unsigned force = cur[32] - base;   // arena-overflow force-scan flag
    const unsigned nou   = cur[16] - base;   // total ovf entries

    // ---- prologue: arm node A fully; arm bkt/cnt for node B ----
    const int nA0 = wave;                        // wave < 4096 < N_NODES
    int pB = nA0 + nwav; if (pB >= N_NODES) pB = N_NODES - 1;

    unsigned cntAa = counts[nA0];
    int bktA  = buckets[nA0 * CAP + m];
    int bkt2A = buckets[nA0 * CAP + 16 + m];     // same 64B line: free
    f16x8 uhA[2];
    load_vh(Uh, (unsigned)nA0, q, uhA);
    unsigned cntB = counts[pB];
    int bktB  = buckets[pB * CAP + m];
    int bkt2B = buckets[pB * CAP + 16 + m];

    f16x8 vA[2];
    {
        unsigned usiA = (unsigned)bktA;
        if (usiA >= N_NODES) usiA = N_NODES - 1;   // poison-safe clamp
        load_vh(Vh, usiA, q, vA);
    }
    f16x8 uhB[2];
    load_vh(Uh, (unsigned)pB, q, uhB);

    for (int n = nA0; n < N_NODES; n += nwav) {
        int pC = n + 2 * nwav; if (pC >= N_NODES) pC = N_NODES - 1;

        // (1) issue V for node B (bktB arrived during previous compute)
        unsigned usiB = (unsigned)bktB;
        if (usiB >= N_NODES) usiB = N_NODES - 1;
        f16x8 vB[2];
        load_vh(Vh, usiB, q, vB);

        // (2) issue bkt/cnt for node C
        unsigned cntC = counts[pC];
        int bktC  = buckets[pC * CAP + m];
        int bkt2C = buckets[pC * CAP + 16 + m];

        // (3) compute node A = n
        const unsigned c = cntAa;
        const int deg = (c < CAP) ? (int)c : CAP;

        float rm[4] = {-INFINITY, -INFINITY, -INFINITY, -INFINITY};
        const int lim0 = (deg < 16) ? deg : 16;
        tile_mfma_max(uhA, vA, w2f, m, q, lim0, rm);      // tile 0 (pre-armed)

        if (deg > 16) {                                   // tile 1: addr pre-armed
            unsigned si2 = (unsigned)bkt2A;               // entry 16+m; garbage
            if (si2 >= N_NODES) si2 = N_NODES - 1;        // rows masked by lim
            f16x8 v2[2];
            load_vh(Vh, si2, q, v2);
            tile_mfma_max(uhA, v2, w2f, m, q, deg - 16, rm);
        }

        if (c > CAP || force != 0u) {   // exact-correctness fallback
            int no = (nou < MAX_OVF) ? (int)nou : MAX_OVF;
            for (int o = 0; o < no; ++o) {
                const int2 ds = ovf[o];
                if (ds.x != n) continue;
                f16x8 vo[2];
                load_vh(Vh, (unsigned)ds.y, q, vo);
                tile_mfma_max(uhA, vo, w2f, m, q, 16, rm);
            }
        }

        // deferred q-reduction (once per node)
#pragma unroll
        for (int t = 0; t < 4; ++t) {
            rm[t] = fmaxf(rm[t], __shfl_xor(rm[t], 16, 64));
            rm[t] = fmaxf(rm[t], __shfl_xor(rm[t], 32, 64));
        }
        const float sel = (q == 0) ? rm[0] : (q == 1) ? rm[1]
                        : (q == 2) ? rm[2] : rm[3];      // col == lane
        out[(size_t)n * 64 + lane] = (c != 0u) ? fast_tanh(sel + b2v) : 0.f;

        // (4) rotate pipeline state; issue U for next B
        cntAa = cntB; cntB = cntC;
        bktB = bktC; bkt2A = bkt2B; bkt2B = bkt2C;
#pragma unroll
        for (int i = 0; i < 2; ++i) { uhA[i] = uhB[i]; vA[i] = vB[i]; }
        load_vh(Uh, (unsigned)pC, q, uhB);               // next iter's B == pC
    }
}

// ---------------------------------------------------------------------------
extern "C" void kernel_launch(void* const* d_in, const int* in_sizes, int n_in,
                              void* d_out, int out_size, void* d_ws, size_t ws_size,
                              hipStream_t stream)
{
    const float* x  = (const float*)d_in[0];
    const int*   ei = (const int*)d_in[1];
    const float* W1 = (const float*)d_in[2];
    const float* b1 = (const float*)d_in[3];
    const float* W2 = (const float*)d_in[4];
    const float* b2 = (const float*)d_in[5];
    float* out = (float*)d_out;

    char* p = (char*)d_ws;
    _Float16* Uh = (_Float16*)p;           p += (size_t)N_NODES * 64 * 2;
    _Float16* Vh = (_Float16*)p;           p += (size_t)N_NODES * 64 * 2;
    unsigned* arena = (unsigned*)p;        p += (size_t)NBIN * KA_BLOCKS * SUBCAP * 4;
    unsigned short* buckets = (unsigned short*)p;
                                           p += (size_t)N_NODES * CAP * 2;
    _Float16* w2f = (_Float16*)p;          p += 64 * 64 * 2;
    unsigned* cntA = (unsigned*)p;         p += (size_t)NBIN * KA_BLOCKS * 4;
    unsigned* counts = (unsigned*)p;       p += (size_t)((N_NODES + 63) / 64) * 64 * 4;
    unsigned* cur = (unsigned*)p;          p += 64 * 4;
    int2* ovf = (int2*)p;                  p += (size_t)MAX_OVF * 8;

    phase1_kernel<<<P1_GRID, 256, 0, stream>>>(x, W1, b1, W2, ei,
                                               Uh, Vh, w2f,
                                               arena, cntA, cur, ovf);
    bucket_kernel<<<NBIN, 1024, 0, stream>>>(arena, cntA, counts, buckets, cur, ovf);
    node_kernel<<<1024, 256, 0, stream>>>(counts, buckets, ovf,
                                          Uh, Vh, w2f, b2, out, cur);
}

// Round 12
// 126.633 us; speedup vs baseline: 1.0551x; 1.0084x over previous
//
#include <hip/hip_runtime.h>
#include <hip/hip_bf16.h>
#include <math.h>

#define N_NODES 50000
#define N_EDGES 800000
#define CAP 32          // bucket row = 32 ushorts = exactly one 64B line
#define MAX_OVF 8192    // overflow list; P(deg>32)~1e-4 -> ~5 nodes, ~50 edges

// Two-phase binning (R8 scatter version — measured best):
#define NBIN 196                    // ceil(N_NODES/256) coarse bins of 256 nodes
#define KA_BLOCKS 256               // binning blocks
#define EPB (N_EDGES / KA_BLOCKS)   // 3125 edges per block (exact)
#define SUBCAP 48                   // per-(bin,block) arena cap: mean 16, sigma 4 -> 8 sigma

#define UV_BLOCKS 256               // MFMA UV-GEMM: 1024 waves, 3125 tiles (~3/wave)
#define W2_BLOCKS 16
#define P1_GRID (KA_BLOCKS + UV_BLOCKS + W2_BLOCKS)

typedef _Float16 f16x8 __attribute__((ext_vector_type(8)));
typedef float f32x4 __attribute__((ext_vector_type(4)));

// ---------------------------------------------------------------------------
// Phase 1 (fused, all independent work) — byte-identical to R8/R11:
//   blocks [0,256):     edge binning -> per-(bin,block) arena chunks (LDS
//                       histogram+rank; zero global atomics common path).
//   blocks [256,512):   UV prep as MFMA GEMM (verified R8).
//   blocks [512,528):   W2 -> f16.
// cur[] poison-base trick: cur[0] untouched = base; cur[16] = ovf cursor;
// cur[32] = arena-overflow force-scan flag.
// ---------------------------------------------------------------------------
__global__ __launch_bounds__(256) void phase1_kernel(
    const float* __restrict__ x, const float* __restrict__ W1,
    const float* __restrict__ b1, const float* __restrict__ W2,
    const int* __restrict__ ei,
    _Float16* __restrict__ Uh, _Float16* __restrict__ Vh,
    _Float16* __restrict__ w2f,
    unsigned* __restrict__ arena, unsigned* __restrict__ cntA,
    unsigned* __restrict__ cur, int2* __restrict__ ovf)
{
    __shared__ unsigned sh_hist[256];
    __shared__ unsigned sh_pack[EPB];        // src | dlow<<16 | bin<<24
    __shared__ unsigned short sh_rank[EPB];  // rank within (block,bin)

    const int blk = blockIdx.x;
    const int tid = threadIdx.x;

    if (blk < KA_BLOCKS) {
        // ---- edge binning ----
        sh_hist[tid] = 0;
        __syncthreads();
        const int e0 = blk * EPB;
        for (int i = tid; i < EPB; i += 256) {
            int s = ei[e0 + i];
            int d = ei[N_EDGES + e0 + i];
            unsigned bin = (unsigned)d >> 8;
            unsigned r = atomicAdd(&sh_hist[bin], 1u);
            sh_pack[i] = (unsigned)s | ((unsigned)(d & 255) << 16) | (bin << 24);
            sh_rank[i] = (unsigned short)r;
        }
        __syncthreads();
        if (tid < NBIN) cntA[tid * KA_BLOCKS + blk] = sh_hist[tid];
        const unsigned base = cur[0];
        for (int i = tid; i < EPB; i += 256) {
            unsigned p = sh_pack[i];
            unsigned r = sh_rank[i];
            unsigned bin = p >> 24;
            if (r < SUBCAP) {
                arena[((size_t)bin * KA_BLOCKS + blk) * SUBCAP + r] = p;
            } else {
                // arena overflow (statistically never): exact fallback
                atomicAdd(&cur[32], 1u);  // force node_kernel to scan ovf
                unsigned o = atomicAdd(&cur[16], 1u) - base;
                int d = (int)(bin * 256 + ((p >> 16) & 255u));
                int s = (int)(p & 0xFFFFu);
                if (o < MAX_OVF) ovf[o] = make_int2(d, s);
            }
        }
    } else if (blk < KA_BLOCKS + UV_BLOCKS) {
        // ---- UV prep via MFMA (verified R8, unchanged) ----
        const int lane = tid & 63;
        const int m = lane & 15;
        const int q = lane >> 4;
        const int wv  = ((blk - KA_BLOCKS) * 256 + tid) >> 6;   // 0..1023
        const int nwv = UV_BLOCKS * 4;

        f16x8 wafr[4][2], wbfr[4][2];
#pragma unroll
        for (int t = 0; t < 4; ++t) {
            const float* w1r = W1 + (size_t)(t * 16 + m) * 128;
#pragma unroll
            for (int s = 0; s < 2; ++s) {
                const int c0 = 32 * s + q * 8;
                float4 pa0 = *(const float4*)(w1r + c0);
                float4 pa1 = *(const float4*)(w1r + c0 + 4);
                float4 pb0 = *(const float4*)(w1r + 64 + c0);
                float4 pb1 = *(const float4*)(w1r + 64 + c0 + 4);
                float av[8] = {pa0.x, pa0.y, pa0.z, pa0.w,
                               pa1.x, pa1.y, pa1.z, pa1.w};
                float bv[8] = {pb0.x, pb0.y, pb0.z, pb0.w,
                               pb1.x, pb1.y, pb1.z, pb1.w};
#pragma unroll
                for (int j = 0; j < 8; ++j) {
                    wafr[t][s][j] = (_Float16)(av[j] - bv[j]);
                    wbfr[t][s][j] = (_Float16)bv[j];
                }
            }
        }
        float biasv[4];
#pragma unroll
        for (int t = 0; t < 4; ++t) biasv[t] = b1[t * 16 + m];

        for (int tile = wv; tile < N_NODES / 16; tile += nwv) {   // 3125 exact
            const float* xr = x + (size_t)(tile * 16 + m) * 64 + q * 8;
            f16x8 a[2];
#pragma unroll
            for (int s = 0; s < 2; ++s) {
                float4 x0 = *(const float4*)(xr + 32 * s);
                float4 x1 = *(const float4*)(xr + 32 * s + 4);
                float xv[8] = {x0.x, x0.y, x0.z, x0.w, x1.x, x1.y, x1.z, x1.w};
#pragma unroll
                for (int j = 0; j < 8; ++j) a[s][j] = (_Float16)xv[j];
            }
#pragma unroll
            for (int t = 0; t < 4; ++t) {
                f32x4 au = {0.f, 0.f, 0.f, 0.f};
                f32x4 aw = {0.f, 0.f, 0.f, 0.f};
                au = __builtin_amdgcn_mfma_f32_16x16x32_f16(a[0], wafr[t][0], au, 0, 0, 0);
                au = __builtin_amdgcn_mfma_f32_16x16x32_f16(a[1], wafr[t][1], au, 0, 0, 0);
                aw = __builtin_amdgcn_mfma_f32_16x16x32_f16(a[0], wbfr[t][0], aw, 0, 0, 0);
                aw = __builtin_amdgcn_mfma_f32_16x16x32_f16(a[1], wbfr[t][1], aw, 0, 0, 0);
#pragma unroll
                for (int r = 0; r < 4; ++r) {
                    const size_t row = (size_t)(tile * 16 + 4 * q + r) * 64;
                    Uh[row + t * 16 + m] = (_Float16)(au[r] + biasv[t]);
                    Vh[row + t * 16 + m] = (_Float16)aw[r];
                }
            }
        }
    } else {
        const int i = (blk - KA_BLOCKS - UV_BLOCKS) * 256 + tid;
        if (i < 64 * 64) w2f[i] = (_Float16)W2[i];
    }
}

// ---------------------------------------------------------------------------
// Phase 2: one block per coarse bin, 1024 threads (R8 version). Thread
// (part,chunk) drains quarter [part*n/4,(part+1)*n/4) of arena chunk 'chunk'
// (slot ORDER within a bucket row is irrelevant for max). Exact counts out.
// ---------------------------------------------------------------------------
__global__ __launch_bounds__(1024) void bucket_kernel(
    const unsigned* __restrict__ arena, const unsigned* __restrict__ cntA,
    unsigned* __restrict__ counts, unsigned short* __restrict__ buckets,
    unsigned* __restrict__ cur, int2* __restrict__ ovf)
{
    __shared__ unsigned lcnt[256];
    const int bin = blockIdx.x;
    const int tid = threadIdx.x;
    if (tid < 256) lcnt[tid] = 0;
    __syncthreads();

    const unsigned base = cur[0];
    const int chunk = tid & 255;
    const int part  = tid >> 8;                        // 0..3
    unsigned n = cntA[(size_t)bin * KA_BLOCKS + chunk];
    if (n > SUBCAP) n = SUBCAP;                        // excess went to ovf
    const unsigned j0 = (n * (unsigned)part) >> 2;
    const unsigned j1 = (n * (unsigned)(part + 1)) >> 2;
    const unsigned* ch = arena + ((size_t)bin * KA_BLOCKS + chunk) * SUBCAP;

    for (unsigned j = j0; j < j1; ++j) {
        unsigned p = ch[j];
        unsigned dlow = (p >> 16) & 255u;
        unsigned s = p & 0xFFFFu;
        unsigned pos = atomicAdd(&lcnt[dlow], 1u);
        int d = bin * 256 + (int)dlow;
        if (pos < CAP) {
            buckets[(size_t)d * CAP + pos] = (unsigned short)s;
        } else {
            unsigned o = atomicAdd(&cur[16], 1u) - base;
            if (o < MAX_OVF) ovf[o] = make_int2(d, (int)s);
        }
    }
    __syncthreads();
    if (tid < 256) {
        const int node = bin * 256 + tid;
        if (node < N_NODES) counts[node] = lcnt[tid];
    }
}

// ---------------------------------------------------------------------------
// Tile compute (all-f16): h = leaky(u+v) in PACKED f16 (v_pk_add/mul/max),
// single-f16 A and B -> 2 MFMAs per output quadrant. Masked max over rows
// 4q+r < lim accumulates into rm[4]; q-reduction hoisted to the caller.
//   A: lane m+16q holds A[m][k]   B: lane n+16q holds W2[n][k]
//   D: lane holds D[4q+r][lane&15]
// ---------------------------------------------------------------------------
__device__ __forceinline__ void tile_mfma_max(
    const f16x8* __restrict__ uh, const f16x8* __restrict__ vv,
    const _Float16* __restrict__ w2f, int m, int q, int lim,
    float* __restrict__ rm)
{
    f16x8 a[2];
#pragma unroll
    for (int s = 0; s < 2; ++s) {
        f16x8 h  = uh[s] + vv[s];
        f16x8 hs = h * (_Float16)0.01f;          // LeakyReLU = max(h, .01h)
#if __has_builtin(__builtin_elementwise_max)
        a[s] = __builtin_elementwise_max(h, hs); // v_pk_max_f16 x4
#else
#pragma unroll
        for (int j = 0; j < 8; ++j)
            a[s][j] = (h[j] > hs[j]) ? h[j] : hs[j];
#endif
    }
#pragma unroll
    for (int t = 0; t < 4; ++t) {
        const f16x8 b0 = *(const f16x8*)(w2f + (t * 16 + m) * 64 + q * 8);
        const f16x8 b1 = *(const f16x8*)(w2f + (t * 16 + m) * 64 + 32 + q * 8);
        f32x4 acc = {0.f, 0.f, 0.f, 0.f};
        acc = __builtin_amdgcn_mfma_f32_16x16x32_f16(a[0], b0, acc, 0, 0, 0);
        acc = __builtin_amdgcn_mfma_f32_16x16x32_f16(a[1], b1, acc, 0, 0, 0);
        float v = -INFINITY;
#pragma unroll
        for (int r = 0; r < 4; ++r)
            if (4 * q + r < lim) v = fmaxf(v, acc[r]);   // mask garbage rows
        rm[t] = fmaxf(rm[t], v);                 // q-reduce deferred to caller
    }
}

// f16 row gather (U and V share the layout): the 4 q-lanes of one row cover
// a full 64B line per instruction.
__device__ __forceinline__ void load_vh(const _Float16* __restrict__ Vh,
                                        unsigned si, int q, f16x8* vv)
{
    const _Float16* b0 = Vh + (size_t)si * 64 + q * 8;
    vv[0] = *(const f16x8*)b0;
    vv[1] = *(const f16x8*)(b0 + 32);
}

// tanh via hw exp + rcp: ~7 VALU vs libm's ~20+.
__device__ __forceinline__ float fast_tanh(float x)
{
    float xc = fminf(fmaxf(x, -12.f), 12.f);
    float e  = __expf(2.f * xc);
    return 1.f - 2.f * __builtin_amdgcn_rcpf(e + 1.f);
}

// ---------------------------------------------------------------------------
// K3: wave per node, 2-deep software pipeline. R12 change: tile-1's V load
// is issued UNCONDITIONALLY in the load phase (address bkt2A pre-armed via
// the pipeline; clamped; garbage rows masked by lim) instead of serially
// behind the deg>16 branch at compute time — hides the ~300-500cy dependent
// gather under tile-0's repack+MFMA for the ~43% of nodes with deg>16.
// Only 8 transient VGPRs live across tile-0 (R4's cross-ITERATION payload
// prefetch was +32 live regs and spilled; this is within-iteration).
// Grid 1024 @ (256,4).
// ---------------------------------------------------------------------------
__global__ __launch_bounds__(256, 4) void node_kernel(
    const unsigned* __restrict__ counts, const unsigned short* __restrict__ buckets,
    const int2* __restrict__ ovf,
    const _Float16* __restrict__ Uh, const _Float16* __restrict__ Vh,
    const _Float16* __restrict__ w2f, const float* __restrict__ b2,
    float* __restrict__ out, const unsigned* __restrict__ cur)
{
    const int lane = threadIdx.x & 63;
    const int m    = lane & 15;
    const int q    = lane >> 4;
    const int wave = (int)((blockIdx.x * blockDim.x + threadIdx.x) >> 6);
    const int nwav = (int)((gridDim.x * blockDim.x) >> 6);

    const float b2v = b2[lane];
    const unsigned base  = cur[0];
    const unsigned force = cur[32] - base;   // arena-overflow force-scan flag
    const unsigned nou   = cur[16] - base;   // total ovf entries

    // ---- prologue: arm node A fully; arm bkt/cnt for node B ----
    const int nA0 = wave;                        // wave < 4096 < N_NODES
    int pB = nA0 + nwav; if (pB >= N_NODES) pB = N_NODES - 1;

    unsigned cntAa = counts[nA0];
    int bktA  = buckets[nA0 * CAP + m];
    int bkt2A = buckets[nA0 * CAP + 16 + m];     // same 64B line: free
    f16x8 uhA[2];
    load_vh(Uh, (unsigned)nA0, q, uhA);
    unsigned cntB = counts[pB];
    int bktB  = buckets[pB * CAP + m];
    int bkt2B = buckets[pB * CAP + 16 + m];

    f16x8 vA[2];
    {
        unsigned usiA = (unsigned)bktA;
        if (usiA >= N_NODES) usiA = N_NODES - 1;   // poison-safe clamp
        load_vh(Vh, usiA, q, vA);
    }
    f16x8 uhB[2];
    load_vh(Uh, (unsigned)pB, q, uhB);

    for (int n = nA0; n < N_NODES; n += nwav) {
        int pC = n + 2 * nwav; if (pC >= N_NODES) pC = N_NODES - 1;

        // (1) issue V for node B (bktB arrived during previous compute)
        unsigned usiB = (unsigned)bktB;
        if (usiB >= N_NODES) usiB = N_NODES - 1;
        f16x8 vB[2];
        load_vh(Vh, usiB, q, vB);

        // (1b) issue tile-1 V for node A unconditionally (addr pre-armed;
        //      overlaps tile-0 compute; ~3.6MB extra fetch for deg<=16 nodes
        //      is free at 13% HBM util)
        f16x8 v2[2];
        {
            unsigned si2 = (unsigned)bkt2A;
            if (si2 >= N_NODES) si2 = N_NODES - 1;
            load_vh(Vh, si2, q, v2);
        }

        // (2) issue bkt/cnt for node C
        unsigned cntC = counts[pC];
        int bktC  = buckets[pC * CAP + m];
        int bkt2C = buckets[pC * CAP + 16 + m];

        // (3) compute node A = n
        const unsigned c = cntAa;
        const int deg = (c < CAP) ? (int)c : CAP;

        float rm[4] = {-INFINITY, -INFINITY, -INFINITY, -INFINITY};
        const int lim0 = (deg < 16) ? deg : 16;
        tile_mfma_max(uhA, vA, w2f, m, q, lim0, rm);      // tile 0 (pre-armed)

        if (deg > 16)                                     // tile 1 (pre-loaded)
            tile_mfma_max(uhA, v2, w2f, m, q, deg - 16, rm);

        if (c > CAP || force != 0u) {   // exact-correctness fallback
            int no = (nou < MAX_OVF) ? (int)nou : MAX_OVF;
            for (int o = 0; o < no; ++o) {
                const int2 ds = ovf[o];
                if (ds.x != n) continue;
                f16x8 vo[2];
                load_vh(Vh, (unsigned)ds.y, q, vo);
                tile_mfma_max(uhA, vo, w2f, m, q, 16, rm);
            }
        }

        // deferred q-reduction (once per node)
#pragma unroll
        for (int t = 0; t < 4; ++t) {
            rm[t] = fmaxf(rm[t], __shfl_xor(rm[t], 16, 64));
            rm[t] = fmaxf(rm[t], __shfl_xor(rm[t], 32, 64));
        }
        const float sel = (q == 0) ? rm[0] : (q == 1) ? rm[1]
                        : (q == 2) ? rm[2] : rm[3];      // col == lane
        out[(size_t)n * 64 + lane] = (c != 0u) ? fast_tanh(sel + b2v) : 0.f;

        // (4) rotate pipeline state; issue U for next B
        cntAa = cntB; cntB = cntC;
        bktB = bktC; bkt2A = bkt2B; bkt2B = bkt2C;
#pragma unroll
        for (int i = 0; i < 2; ++i) { uhA[i] = uhB[i]; vA[i] = vB[i]; }
        load_vh(Uh, (unsigned)pC, q, uhB);               // next iter's B == pC
    }
}

// ---------------------------------------------------------------------------
extern "C" void kernel_launch(void* const* d_in, const int* in_sizes, int n_in,
                              void* d_out, int out_size, void* d_ws, size_t ws_size,
                              hipStream_t stream)
{
    const float* x  = (const float*)d_in[0];
    const int*   ei = (const int*)d_in[1];
    const float* W1 = (const float*)d_in[2];
    const float* b1 = (const float*)d_in[3];
    const float* W2 = (const float*)d_in[4];
    const float* b2 = (const float*)d_in[5];
    float* out = (float*)d_out;

    char* p = (char*)d_ws;
    _Float16* Uh = (_Float16*)p;           p += (size_t)N_NODES * 64 * 2;
    _Float16* Vh = (_Float16*)p;           p += (size_t)N_NODES * 64 * 2;
    unsigned* arena = (unsigned*)p;        p += (size_t)NBIN * KA_BLOCKS * SUBCAP * 4;
    unsigned short* buckets = (unsigned short*)p;
                                           p += (size_t)N_NODES * CAP * 2;
    _Float16* w2f = (_Float16*)p;          p += 64 * 64 * 2;
    unsigned* cntA = (unsigned*)p;         p += (size_t)NBIN * KA_BLOCKS * 4;
    unsigned* counts = (unsigned*)p;       p += (size_t)((N_NODES + 63) / 64) * 64 * 4;
    unsigned* cur = (unsigned*)p;          p += 64 * 4;
    int2* ovf = (int2*)p;                  p += (size_t)MAX_OVF * 8;

    phase1_kernel<<<P1_GRID, 256, 0, stream>>>(x, W1, b1, W2, ei,
                                               Uh, Vh, w2f,
                                               arena, cntA, cur, ovf);
    bucket_kernel<<<NBIN, 1024, 0, stream>>>(arena, cntA, counts, buckets, cur, ovf);
    node_kernel<<<1024, 256, 0, stream>>>(counts, buckets, ovf,
                                          Uh, Vh, w2f, b2, out, cur);
}